// Round 1
// baseline (540.616 us; speedup 1.0000x reference)
//
#include <hip/hip_runtime.h>

typedef __attribute__((ext_vector_type(8))) short short8;
typedef __attribute__((ext_vector_type(4))) float f32x4;
typedef __attribute__((ext_vector_type(4))) unsigned short us4;

__device__ __forceinline__ unsigned short f2b(float f) {
  unsigned int u = __float_as_uint(f);
  u += 0x7FFFu + ((u >> 16) & 1u);
  return (unsigned short)(u >> 16);
}

// Convert in_proj_w (768x256) and out_proj_w (256x256) fp32 -> bf16 into ws.
// 262144 elements total, 4 per thread, 65536 threads.
__global__ void prep_weights(const float* __restrict__ wq,
                             const float* __restrict__ wo,
                             unsigned short* __restrict__ dst) {
  int idx = blockIdx.x * blockDim.x + threadIdx.x;
  int e = idx * 4;
  float4 v;
  if (e < 196608) v = *(const float4*)(wq + e);
  else            v = *(const float4*)(wo + (e - 196608));
  us4 o;
  o.x = f2b(v.x); o.y = f2b(v.y); o.z = f2b(v.z); o.w = f2b(v.w);
  *(us4*)(dst + e) = o;
}

// One workgroup (512 threads, 8 waves) per window. 4096 windows.
// LDS: x_norm bf16 [64][264] (33792 B) + scratch (29696 B) = 63488 B.
// Scratch layout (elements of u16):
//   QKV phase : q0@0 q1@2560 k0@5120 k1@7680 (each [64][40]) vT0@10240 vT1@12544 (each [32][72])
//   attn      : P0@0 P1@4608 (each [64][72])   (overwrites q/k after barrier)
//   out_proj  : A_hg@0 ([64][72], cols = 2 heads x 32)       (overwrites P after barrier)
__global__ __launch_bounds__(512) void grid_attn(
    const float* __restrict__ x,
    const float* __restrict__ ln_w,
    const float* __restrict__ ln_b,
    const unsigned short* __restrict__ Wqkv,   // [768][256] bf16
    const float* __restrict__ bqkv,            // [768]
    const unsigned short* __restrict__ Wout,   // [256][256] bf16
    const float* __restrict__ bout,            // [256]
    const float* __restrict__ gamma,           // [256]
    float* __restrict__ out) {

  __shared__ unsigned short ldsX[64 * 264];
  __shared__ unsigned short ldsS[14848];

  const int tid = threadIdx.x;
  const int w   = tid >> 6;      // wave 0..7
  const int lid = tid & 63;
  const int l16 = lid & 15;
  const int lhi = lid >> 4;      // 0..3

  const int n  = blockIdx.x;
  const int b  = n >> 8;
  const int wi = (n >> 4) & 15;  // i (row offset within 16-block)
  const int wj = n & 15;         // j

  // ---------- LayerNorm + gather into ldsX (bf16) ----------
  {
    float4 lwv = *(const float4*)(ln_w + lid * 4);
    float4 lbv = *(const float4*)(ln_b + lid * 4);
    for (int t = 0; t < 8; ++t) {
      int l  = w * 8 + t;                 // token in window
      int a  = l >> 3, cg = l & 7;
      int hh = a * 16 + wi, ww = cg * 16 + wj;
      const float4 v = *(const float4*)(x + ((size_t)((b * 128 + hh) * 128 + ww)) * 256 + lid * 4);
      float s1 = v.x + v.y + v.z + v.w;
      float s2 = v.x * v.x + v.y * v.y + v.z * v.z + v.w * v.w;
      #pragma unroll
      for (int m = 32; m >= 1; m >>= 1) {
        s1 += __shfl_xor(s1, m);
        s2 += __shfl_xor(s2, m);
      }
      float mu  = s1 * (1.0f / 256.0f);
      float var = s2 * (1.0f / 256.0f) - mu * mu;
      float rs  = rsqrtf(var + 1e-5f);
      us4 o;
      o.x = f2b((v.x - mu) * rs * lwv.x + lbv.x);
      o.y = f2b((v.y - mu) * rs * lwv.y + lbv.y);
      o.z = f2b((v.z - mu) * rs * lwv.z + lbv.z);
      o.w = f2b((v.w - mu) * rs * lwv.w + lbv.w);
      *(us4*)(&ldsX[l * 264 + lid * 4]) = o;
    }
  }
  __syncthreads();

  // persistent out_proj accumulators: wave owns out channels [32w, 32w+32)
  f32x4 oacc[4][2];
  #pragma unroll
  for (int mt = 0; mt < 4; ++mt)
    #pragma unroll
    for (int nt = 0; nt < 2; ++nt)
      oacc[mt][nt] = (f32x4){0.f, 0.f, 0.f, 0.f};

  const int wm = w >> 2;  // QKV: M-half     | attn: head-in-group
  const int wn = w & 3;   // QKV: N-quarter  | attn: 16-row block

  for (int grp = 0; grp < 4; ++grp) {
    // ---------- QKV partial GEMM: M=64, N=192 (q|k|v for 2 heads), K=256 ----------
    f32x4 qacc[2][3];
    #pragma unroll
    for (int mt = 0; mt < 2; ++mt)
      #pragma unroll
      for (int nt = 0; nt < 3; ++nt)
        qacc[mt][nt] = (f32x4){0.f, 0.f, 0.f, 0.f};

    #pragma unroll
    for (int kc = 0; kc < 8; ++kc) {
      short8 af0 = *(const short8*)(&ldsX[(wm * 32 + 0  + l16) * 264 + kc * 32 + lhi * 8]);
      short8 af1 = *(const short8*)(&ldsX[(wm * 32 + 16 + l16) * 264 + kc * 32 + lhi * 8]);
      #pragma unroll
      for (int nt = 0; nt < 3; ++nt) {
        int n0 = wn * 48 + nt * 16;
        int wrow = (n0 >> 6) * 256 + grp * 64 + (n0 & 63) + l16;
        short8 bf = *(const short8*)(&Wqkv[(size_t)wrow * 256 + kc * 32 + lhi * 8]);
        qacc[0][nt] = __builtin_amdgcn_mfma_f32_16x16x32_bf16(af0, bf, qacc[0][nt], 0, 0, 0);
        qacc[1][nt] = __builtin_amdgcn_mfma_f32_16x16x32_bf16(af1, bf, qacc[1][nt], 0, 0, 0);
      }
    }

    __syncthreads();  // prev group's A_hg reads complete before scratch overwrite

    // write q,k (row-major [64][40]) and v^T ([32][72]) to scratch, + bias, bf16
    #pragma unroll
    for (int nt = 0; nt < 3; ++nt) {
      int n0  = wn * 48 + nt * 16;
      int mat = n0 >> 6;          // 0=q 1=k 2=v
      int hdn = (n0 >> 5) & 1;    // head in group
      int d0  = n0 & 31;          // 0 or 16
      float bias = bqkv[mat * 256 + grp * 64 + (n0 & 63) + l16];
      #pragma unroll
      for (int mt = 0; mt < 2; ++mt)
        #pragma unroll
        for (int r = 0; r < 4; ++r) {
          int row = wm * 32 + mt * 16 + lhi * 4 + r;
          unsigned short bv = f2b(qacc[mt][nt][r] + bias);
          if (mat < 2) {
            ldsS[mat * 5120 + hdn * 2560 + row * 40 + d0 + l16] = bv;
          } else {
            ldsS[10240 + hdn * 2304 + (d0 + l16) * 72 + row] = bv;
          }
        }
    }
    __syncthreads();

    // ---------- scores + softmax (head = wm, rows = wn*16..+15) ----------
    unsigned short pbf[4][4];
    {
      short8 aq = *(const short8*)(&ldsS[wm * 2560 + (wn * 16 + l16) * 40 + lhi * 8]);
      f32x4 sc[4];
      #pragma unroll
      for (int nt = 0; nt < 4; ++nt) {
        short8 bk = *(const short8*)(&ldsS[5120 + wm * 2560 + (nt * 16 + l16) * 40 + lhi * 8]);
        sc[nt] = __builtin_amdgcn_mfma_f32_16x16x32_bf16(aq, bk, (f32x4){0.f,0.f,0.f,0.f}, 0, 0, 0);
      }
      #pragma unroll
      for (int r = 0; r < 4; ++r) {
        float mx = fmaxf(fmaxf(sc[0][r], sc[1][r]), fmaxf(sc[2][r], sc[3][r]));
        #pragma unroll
        for (int m = 8; m >= 1; m >>= 1) mx = fmaxf(mx, __shfl_xor(mx, m));
        float e0 = __expf((sc[0][r] - mx) * 0.17677669529663687f);
        float e1 = __expf((sc[1][r] - mx) * 0.17677669529663687f);
        float e2 = __expf((sc[2][r] - mx) * 0.17677669529663687f);
        float e3 = __expf((sc[3][r] - mx) * 0.17677669529663687f);
        float sum = e0 + e1 + e2 + e3;
        #pragma unroll
        for (int m = 8; m >= 1; m >>= 1) sum += __shfl_xor(sum, m);
        float inv = 1.0f / sum;
        pbf[0][r] = f2b(e0 * inv);
        pbf[1][r] = f2b(e1 * inv);
        pbf[2][r] = f2b(e2 * inv);
        pbf[3][r] = f2b(e3 * inv);
      }
    }
    __syncthreads();  // all q,k reads done before P overwrites them
    #pragma unroll
    for (int nt = 0; nt < 4; ++nt)
      #pragma unroll
      for (int r = 0; r < 4; ++r)
        ldsS[wm * 4608 + (wn * 16 + lhi * 4 + r) * 72 + nt * 16 + l16] = pbf[nt][r];
    __syncthreads();

    // ---------- PV: out 16x32 per wave ----------
    f32x4 ov[2];
    ov[0] = (f32x4){0.f,0.f,0.f,0.f};
    ov[1] = (f32x4){0.f,0.f,0.f,0.f};
    #pragma unroll
    for (int kc = 0; kc < 2; ++kc) {
      short8 ap = *(const short8*)(&ldsS[wm * 4608 + (wn * 16 + l16) * 72 + kc * 32 + lhi * 8]);
      #pragma unroll
      for (int nt = 0; nt < 2; ++nt) {
        short8 bv = *(const short8*)(&ldsS[10240 + wm * 2304 + (nt * 16 + l16) * 72 + kc * 32 + lhi * 8]);
        ov[nt] = __builtin_amdgcn_mfma_f32_16x16x32_bf16(ap, bv, ov[nt], 0, 0, 0);
      }
    }
    __syncthreads();  // all P,v reads done before A_hg overwrites P0
    #pragma unroll
    for (int nt = 0; nt < 2; ++nt)
      #pragma unroll
      for (int r = 0; r < 4; ++r)
        ldsS[(wn * 16 + lhi * 4 + r) * 72 + wm * 32 + nt * 16 + l16] = f2b(ov[nt][r]);
    __syncthreads();

    // ---------- out_proj partial: K-slice = grp*64 ----------
    #pragma unroll
    for (int kc = 0; kc < 2; ++kc) {
      short8 aa[4];
      #pragma unroll
      for (int mt = 0; mt < 4; ++mt)
        aa[mt] = *(const short8*)(&ldsS[(mt * 16 + l16) * 72 + kc * 32 + lhi * 8]);
      #pragma unroll
      for (int nt = 0; nt < 2; ++nt) {
        short8 bw = *(const short8*)(&Wout[(size_t)(w * 32 + nt * 16 + l16) * 256 + grp * 64 + kc * 32 + lhi * 8]);
        #pragma unroll
        for (int mt = 0; mt < 4; ++mt)
          oacc[mt][nt] = __builtin_amdgcn_mfma_f32_16x16x32_bf16(aa[mt], bw, oacc[mt][nt], 0, 0, 0);
      }
    }
  }

  // ---------- epilogue: + out_bias, * gamma, scatter ----------
  float ob0 = bout[w * 32 + l16];
  float ob1 = bout[w * 32 + 16 + l16];
  float g0  = gamma[w * 32 + l16];
  float g1  = gamma[w * 32 + 16 + l16];
  #pragma unroll
  for (int mt = 0; mt < 4; ++mt)
    #pragma unroll
    for (int r = 0; r < 4; ++r) {
      int row = mt * 16 + lhi * 4 + r;
      int a = row >> 3, cg = row & 7;
      int hh = a * 16 + wi, ww2 = cg * 16 + wj;
      float* po = out + ((size_t)((b * 128 + hh) * 128 + ww2)) * 256 + w * 32;
      po[l16]      = (oacc[mt][0][r] + ob0) * g0;
      po[l16 + 16] = (oacc[mt][1][r] + ob1) * g1;
    }
}

extern "C" void kernel_launch(void* const* d_in, const int* in_sizes, int n_in,
                              void* d_out, int out_size, void* d_ws, size_t ws_size,
                              hipStream_t stream) {
  const float* x    = (const float*)d_in[0];
  const float* ln_w = (const float*)d_in[1];
  const float* ln_b = (const float*)d_in[2];
  const float* ipw  = (const float*)d_in[3];
  const float* ipb  = (const float*)d_in[4];
  const float* opw  = (const float*)d_in[5];
  const float* opb  = (const float*)d_in[6];
  const float* gm   = (const float*)d_in[7];

  unsigned short* wbf = (unsigned short*)d_ws;   // [0,196608): Wqkv bf16, [196608,262144): Wout bf16

  prep_weights<<<256, 256, 0, stream>>>(ipw, opw, wbf);
  grid_attn<<<4096, 512, 0, stream>>>(x, ln_w, ln_b,
                                      wbf, ipb,
                                      wbf + 196608, opb,
                                      gm, (float*)d_out);
}

// Round 2
// 358.801 us; speedup vs baseline: 1.5067x; 1.5067x over previous
//
#include <hip/hip_runtime.h>

typedef __attribute__((ext_vector_type(8))) short short8;
typedef __attribute__((ext_vector_type(4))) float f32x4;
typedef __attribute__((ext_vector_type(4))) unsigned short us4;

__device__ __forceinline__ unsigned short f2b(float f) {
  unsigned int u = __float_as_uint(f);
  u += 0x7FFFu + ((u >> 16) & 1u);
  return (unsigned short)(u >> 16);
}

// Convert in_proj_w (768x256) and out_proj_w (256x256) fp32 -> bf16 into ws.
__global__ void prep_weights(const float* __restrict__ wq,
                             const float* __restrict__ wo,
                             unsigned short* __restrict__ dst) {
  int idx = blockIdx.x * blockDim.x + threadIdx.x;
  int e = idx * 4;
  float4 v;
  if (e < 196608) v = *(const float4*)(wq + e);
  else            v = *(const float4*)(wo + (e - 196608));
  us4 o;
  o.x = f2b(v.x); o.y = f2b(v.y); o.z = f2b(v.z); o.w = f2b(v.w);
  *(us4*)(dst + e) = o;
}

// One workgroup (512 threads, 8 waves) per window; wave w owns head w.
// LDS: ldsX [64][264] bf16 (x_norm; later reused for attention-out)  33792 B
//      ldsB [8][1152]  per-wave bounce buffers                       18432 B
// Barriers: 3 total (after LN, before A_out overwrite, before out_proj).
__global__ __launch_bounds__(512, 4) void grid_attn(
    const float* __restrict__ x,
    const float* __restrict__ ln_w,
    const float* __restrict__ ln_b,
    const unsigned short* __restrict__ Wqkv,   // [768][256] bf16
    const float* __restrict__ bqkv,            // [768]
    const unsigned short* __restrict__ Wout,   // [256][256] bf16
    const float* __restrict__ bout,            // [256]
    const float* __restrict__ gamma,           // [256]
    float* __restrict__ out) {

  __shared__ unsigned short ldsX[64 * 264];
  __shared__ unsigned short ldsB[8][1152];

  const int tid = threadIdx.x;
  const int w   = tid >> 6;      // wave = head
  const int lid = tid & 63;
  const int l16 = lid & 15;
  const int lhi = lid >> 4;      // 0..3

  const int n  = blockIdx.x;
  const int b  = n >> 8;
  const int wi = (n >> 4) & 15;
  const int wj = n & 15;

  // ---------- LayerNorm + gather into ldsX (bf16) ----------
  {
    float4 lwv = *(const float4*)(ln_w + lid * 4);
    float4 lbv = *(const float4*)(ln_b + lid * 4);
    #pragma unroll
    for (int t = 0; t < 8; ++t) {
      int l  = w * 8 + t;
      int a  = l >> 3, cg = l & 7;
      int hh = a * 16 + wi, ww = cg * 16 + wj;
      const float4 v = *(const float4*)(x + ((size_t)((b * 128 + hh) * 128 + ww)) * 256 + lid * 4);
      float s1 = v.x + v.y + v.z + v.w;
      float s2 = v.x * v.x + v.y * v.y + v.z * v.z + v.w * v.w;
      #pragma unroll
      for (int m = 32; m >= 1; m >>= 1) {
        s1 += __shfl_xor(s1, m);
        s2 += __shfl_xor(s2, m);
      }
      float mu  = s1 * (1.0f / 256.0f);
      float var = s2 * (1.0f / 256.0f) - mu * mu;
      float rs  = rsqrtf(var + 1e-5f);
      us4 o;
      o.x = f2b((v.x - mu) * rs * lwv.x + lbv.x);
      o.y = f2b((v.y - mu) * rs * lwv.y + lbv.y);
      o.z = f2b((v.z - mu) * rs * lwv.z + lbv.z);
      o.w = f2b((v.w - mu) * rs * lwv.w + lbv.w);
      *(us4*)(&ldsX[l * 264 + lid * 4]) = o;
    }
  }
  __syncthreads();

  unsigned short* bb = &ldsB[w][0];

  // ---------- QK phase: qT = Wq · xT, kT = Wk · xT  (C: col=token, row=dim) ----------
  f32x4 qa[2][4], ka[2][4];   // [dimtile][toktile]
  #pragma unroll
  for (int dt = 0; dt < 2; ++dt)
    #pragma unroll
    for (int tt = 0; tt < 4; ++tt) {
      qa[dt][tt] = (f32x4){0.f, 0.f, 0.f, 0.f};
      ka[dt][tt] = (f32x4){0.f, 0.f, 0.f, 0.f};
    }
  #pragma unroll
  for (int kc = 0; kc < 8; ++kc) {
    short8 xf[4];
    #pragma unroll
    for (int tt = 0; tt < 4; ++tt)
      xf[tt] = *(const short8*)(&ldsX[(tt * 16 + l16) * 264 + kc * 32 + lhi * 8]);
    short8 wq[2], wk[2];
    #pragma unroll
    for (int dt = 0; dt < 2; ++dt) {
      wq[dt] = *(const short8*)(&Wqkv[(size_t)(w * 32 + dt * 16 + l16) * 256 + kc * 32 + lhi * 8]);
      wk[dt] = *(const short8*)(&Wqkv[(size_t)(256 + w * 32 + dt * 16 + l16) * 256 + kc * 32 + lhi * 8]);
    }
    #pragma unroll
    for (int dt = 0; dt < 2; ++dt)
      #pragma unroll
      for (int tt = 0; tt < 4; ++tt) {
        qa[dt][tt] = __builtin_amdgcn_mfma_f32_16x16x32_bf16(wq[dt], xf[tt], qa[dt][tt], 0, 0, 0);
        ka[dt][tt] = __builtin_amdgcn_mfma_f32_16x16x32_bf16(wk[dt], xf[tt], ka[dt][tt], 0, 0, 0);
      }
  }

  // ---------- bounce qT,kT -> row-major frags (lane=token, k=dim) ----------
  short8 qf[4], kf[4];
  {
    f32x4 bqv[2], bkv[2];
    #pragma unroll
    for (int dt = 0; dt < 2; ++dt) {
      bqv[dt] = *(const f32x4*)(bqkv + w * 32 + dt * 16 + lhi * 4);
      bkv[dt] = *(const f32x4*)(bqkv + 256 + w * 32 + dt * 16 + lhi * 4);
    }
    #pragma unroll
    for (int tt = 0; tt < 4; ++tt) {
      #pragma unroll
      for (int dt = 0; dt < 2; ++dt)
        #pragma unroll
        for (int r = 0; r < 4; ++r)
          bb[l16 * 40 + dt * 16 + lhi * 4 + r] = f2b(qa[dt][tt][r] + bqv[dt][r]);
      qf[tt] = *(const short8*)(&bb[l16 * 40 + lhi * 8]);
    }
    #pragma unroll
    for (int tt = 0; tt < 4; ++tt) {
      #pragma unroll
      for (int dt = 0; dt < 2; ++dt)
        #pragma unroll
        for (int r = 0; r < 4; ++r)
          bb[l16 * 40 + dt * 16 + lhi * 4 + r] = f2b(ka[dt][tt][r] + bkv[dt][r]);
      kf[tt] = *(const short8*)(&bb[l16 * 40 + lhi * 8]);
    }
  }

  // ---------- S^T = K·Q^T  (C: col=q-token, row=k-token) ----------
  f32x4 sc[4][4];   // [kt-tile][qt-tile]
  #pragma unroll
  for (int m = 0; m < 4; ++m)
    #pragma unroll
    for (int nn = 0; nn < 4; ++nn)
      sc[m][nn] = __builtin_amdgcn_mfma_f32_16x16x32_bf16(kf[m], qf[nn], (f32x4){0.f,0.f,0.f,0.f}, 0, 0, 0);

  // ---------- softmax over k (4-lane groups share q-col l16) + P frags ----------
  short8 pf[4][2];   // [qt-tile][kc]
  const float scale = 0.17677669529663687f;
  #pragma unroll
  for (int nn = 0; nn < 4; ++nn) {
    float mx = sc[0][nn][0];
    #pragma unroll
    for (int m = 0; m < 4; ++m)
      #pragma unroll
      for (int r = 0; r < 4; ++r)
        mx = fmaxf(mx, sc[m][nn][r]);
    mx = fmaxf(mx, __shfl_xor(mx, 16));
    mx = fmaxf(mx, __shfl_xor(mx, 32));
    float e[4][4], sum = 0.f;
    #pragma unroll
    for (int m = 0; m < 4; ++m)
      #pragma unroll
      for (int r = 0; r < 4; ++r) {
        e[m][r] = __expf((sc[m][nn][r] - mx) * scale);
        sum += e[m][r];
      }
    sum += __shfl_xor(sum, 16);
    sum += __shfl_xor(sum, 32);
    float inv = 1.0f / sum;
    #pragma unroll
    for (int m = 0; m < 4; ++m)
      #pragma unroll
      for (int r = 0; r < 4; ++r)
        bb[l16 * 72 + m * 16 + lhi * 4 + r] = f2b(e[m][r] * inv);
    pf[nn][0] = *(const short8*)(&bb[l16 * 72 + lhi * 8]);
    pf[nn][1] = *(const short8*)(&bb[l16 * 72 + 32 + lhi * 8]);
  }

  // ---------- V phase: v = x · Wv^T  (C: col=dim, row=token) ----------
  f32x4 va[4][2];   // [toktile][dimtile]
  #pragma unroll
  for (int tt = 0; tt < 4; ++tt)
    #pragma unroll
    for (int dt = 0; dt < 2; ++dt)
      va[tt][dt] = (f32x4){0.f, 0.f, 0.f, 0.f};
  #pragma unroll
  for (int kc = 0; kc < 8; ++kc) {
    short8 xf[4];
    #pragma unroll
    for (int tt = 0; tt < 4; ++tt)
      xf[tt] = *(const short8*)(&ldsX[(tt * 16 + l16) * 264 + kc * 32 + lhi * 8]);
    short8 wv[2];
    #pragma unroll
    for (int dt = 0; dt < 2; ++dt)
      wv[dt] = *(const short8*)(&Wqkv[(size_t)(512 + w * 32 + dt * 16 + l16) * 256 + kc * 32 + lhi * 8]);
    #pragma unroll
    for (int tt = 0; tt < 4; ++tt)
      #pragma unroll
      for (int dt = 0; dt < 2; ++dt)
        va[tt][dt] = __builtin_amdgcn_mfma_f32_16x16x32_bf16(xf[tt], wv[dt], va[tt][dt], 0, 0, 0);
  }

  // ---------- bounce v -> B-frags (lane=dim, k=token) ----------
  short8 vf[2][2];   // [dimtile][kc]
  {
    float bvs[2];
    #pragma unroll
    for (int dt = 0; dt < 2; ++dt) bvs[dt] = bqkv[512 + w * 32 + dt * 16 + l16];
    #pragma unroll
    for (int dt = 0; dt < 2; ++dt) {
      #pragma unroll
      for (int tt = 0; tt < 4; ++tt)
        #pragma unroll
        for (int r = 0; r < 4; ++r)
          bb[l16 * 72 + tt * 16 + lhi * 4 + r] = f2b(va[tt][dt][r] + bvs[dt]);
      vf[dt][0] = *(const short8*)(&bb[l16 * 72 + lhi * 8]);
      vf[dt][1] = *(const short8*)(&bb[l16 * 72 + 32 + lhi * 8]);
    }
  }

  // ---------- PV: out = P · V  (C: col=dim, row=q-token) ----------
  f32x4 oa[4][2];   // [qt-tile][dimtile]
  #pragma unroll
  for (int nn = 0; nn < 4; ++nn)
    #pragma unroll
    for (int dt = 0; dt < 2; ++dt)
      oa[nn][dt] = (f32x4){0.f, 0.f, 0.f, 0.f};
  #pragma unroll
  for (int kc = 0; kc < 2; ++kc)
    #pragma unroll
    for (int nn = 0; nn < 4; ++nn)
      #pragma unroll
      for (int dt = 0; dt < 2; ++dt)
        oa[nn][dt] = __builtin_amdgcn_mfma_f32_16x16x32_bf16(pf[nn][kc], vf[dt][kc], oa[nn][dt], 0, 0, 0);

  __syncthreads();   // all ldsX reads (V phase) complete before A_out overwrite

  // ---------- stage attention-out into ldsX region ([64 tok][264], bf16) ----------
  #pragma unroll
  for (int nn = 0; nn < 4; ++nn)
    #pragma unroll
    for (int dt = 0; dt < 2; ++dt)
      #pragma unroll
      for (int r = 0; r < 4; ++r)
        ldsX[(nn * 16 + lhi * 4 + r) * 264 + w * 32 + dt * 16 + l16] = f2b(oa[nn][dt][r]);
  __syncthreads();

  // ---------- out_proj: Y = A_out · Wout^T, wave owns outc [32w,32w+32) ----------
  f32x4 ya[4][2];
  #pragma unroll
  for (int mt = 0; mt < 4; ++mt)
    #pragma unroll
    for (int nt = 0; nt < 2; ++nt)
      ya[mt][nt] = (f32x4){0.f, 0.f, 0.f, 0.f};
  #pragma unroll
  for (int kc = 0; kc < 8; ++kc) {
    short8 af[4];
    #pragma unroll
    for (int mt = 0; mt < 4; ++mt)
      af[mt] = *(const short8*)(&ldsX[(mt * 16 + l16) * 264 + kc * 32 + lhi * 8]);
    short8 wf[2];
    #pragma unroll
    for (int nt = 0; nt < 2; ++nt)
      wf[nt] = *(const short8*)(&Wout[(size_t)(w * 32 + nt * 16 + l16) * 256 + kc * 32 + lhi * 8]);
    #pragma unroll
    for (int mt = 0; mt < 4; ++mt)
      #pragma unroll
      for (int nt = 0; nt < 2; ++nt)
        ya[mt][nt] = __builtin_amdgcn_mfma_f32_16x16x32_bf16(af[mt], wf[nt], ya[mt][nt], 0, 0, 0);
  }

  // ---------- epilogue: + out_bias, * gamma, scatter ----------
  float ob0 = bout[w * 32 + l16];
  float ob1 = bout[w * 32 + 16 + l16];
  float g0  = gamma[w * 32 + l16];
  float g1  = gamma[w * 32 + 16 + l16];
  #pragma unroll
  for (int mt = 0; mt < 4; ++mt)
    #pragma unroll
    for (int r = 0; r < 4; ++r) {
      int row = mt * 16 + lhi * 4 + r;
      int a = row >> 3, cg = row & 7;
      int hh = a * 16 + wi, ww2 = cg * 16 + wj;
      float* po = out + ((size_t)((b * 128 + hh) * 128 + ww2)) * 256 + w * 32;
      po[l16]      = (ya[mt][0][r] + ob0) * g0;
      po[l16 + 16] = (ya[mt][1][r] + ob1) * g1;
    }
}

extern "C" void kernel_launch(void* const* d_in, const int* in_sizes, int n_in,
                              void* d_out, int out_size, void* d_ws, size_t ws_size,
                              hipStream_t stream) {
  const float* x    = (const float*)d_in[0];
  const float* ln_w = (const float*)d_in[1];
  const float* ln_b = (const float*)d_in[2];
  const float* ipw  = (const float*)d_in[3];
  const float* ipb  = (const float*)d_in[4];
  const float* opw  = (const float*)d_in[5];
  const float* opb  = (const float*)d_in[6];
  const float* gm   = (const float*)d_in[7];

  unsigned short* wbf = (unsigned short*)d_ws;

  prep_weights<<<256, 256, 0, stream>>>(ipw, opw, wbf);
  grid_attn<<<4096, 512, 0, stream>>>(x, ln_w, ln_b,
                                      wbf, ipb,
                                      wbf + 196608, opb,
                                      gm, (float*)d_out);
}